// Round 3
// baseline (1573.267 us; speedup 1.0000x reference)
//
#include <hip/hip_runtime.h>
#include <math.h>

// VectorCapsules fused v3 — one 1024-thread workgroup per batch element.
// Changes vs v2: u[] lives in per-thread REGISTERS (routing reuses phase-2
// ownership), Wp staged per-gi into LDS transposed [c][i] (wave-uniform
// broadcast reads), 16 waves/CU occupancy, LDS 73KB (was 152KB).

#define NTH    1024
#define NW     16        // waves per block
#define IC     6272      // 32*14*14 capsules
#define NCLS   5

__global__ __launch_bounds__(NTH)
void caps_fused(const float* __restrict__ inp,
                const float* __restrict__ W1,
                const float* __restrict__ b1,
                const float* __restrict__ Wp,
                const float* __restrict__ bp,
                const float* __restrict__ capsW,
                const float* __restrict__ broute,
                float* __restrict__ out)
{
    extern __shared__ float lds[];
    float* s_in  = lds;              // 3481
    float* s_W1  = s_in + 3481;      // 800
    float* s_b1  = s_W1 + 800;       // 32
    float* s_bp  = s_b1 + 32;        // 448
    float* s_xs  = s_bp + 448;       // 6272 : xs[c][hw], 32 x 196
    float* s_wp  = s_xs + 6272;      // 7168 : per-gi Wp slices, [wave][c][i] = [16][32][14]
    float* s_red = s_wp + 7168;      // 80 (16 waves x 5)
    float* s_v   = s_red + 80;       // 8 (5 used)

    const int b    = blockIdx.x;
    const int tid  = threadIdx.x;
    const int lane = tid & 63;
    const int wv   = tid >> 6;

    // ---------------- Phase 0: stage ----------------
    const float* inb = inp + (size_t)b * (59 * 59);
    for (int i = tid; i < 59 * 59; i += NTH) s_in[i] = inb[i];
    for (int i = tid; i < 800;     i += NTH) s_W1[i] = W1[i];
    if (tid < 32) s_b1[tid] = b1[tid];
    if (tid < 448) s_bp[tid] = bp[tid];
    __syncthreads();

    // ---------------- Phase 1: conv (only ::2,::2 outputs => stride 4) ----
    for (int n = tid; n < IC; n += NTH) {
        const int c  = n / 196;
        const int hw = n - c * 196;
        const int h  = hw / 14;
        const int w  = hw - h * 14;
        const float* ip = s_in + (4 * h) * 59 + 4 * w;
        const float* wk = s_W1 + c * 25;
        float acc = s_b1[c];
        #pragma unroll
        for (int kh = 0; kh < 5; ++kh)
            #pragma unroll
            for (int kw = 0; kw < 5; ++kw)
                acc = fmaf(ip[kh * 59 + kw], wk[kh * 5 + kw], acc);
        s_xs[n] = fmaxf(acc, 0.0f);
    }

    // ---------------- Phase 2: pc -> squash -> u (registers) ----------------
    // wave wv handles g = wv + gi*16, gi in {0,1}; lane covers hw in 4 rounds.
    float u[2][4][NCLS];   // per-thread capsule outputs (static indexing only)

    #pragma unroll
    for (int gi = 0; gi < 2; ++gi) {
        // stage Wp slices for this gi: s_wp[slice][c][i] = Wp[(slice+gi*16)*448 + i*32 + c]
        __syncthreads();   // previous users of s_wp / s_xs writers done
        for (int idx = tid; idx < 16 * 448; idx += NTH) {
            const int c     = idx & 31;          // fastest -> coalesced global read
            const int i     = (idx >> 5) % 14;
            const int slice = idx / 448;
            s_wp[slice * 448 + c * 14 + i] = Wp[(size_t)(slice + gi * 16) * 448 + i * 32 + c];
        }
        __syncthreads();

        const int g = wv + gi * 16;
        const float* wpb = s_wp + wv * 448;
        float pc0[14], pc1[14], pc2[14], pc3[14];
        #pragma unroll
        for (int i = 0; i < 14; ++i) {
            const float bias = s_bp[g * 14 + i];
            pc0[i] = bias; pc1[i] = bias; pc2[i] = bias; pc3[i] = bias;
        }
        for (int c = 0; c < 32; ++c) {
            const float* xc = s_xs + c * 196;
            const float x0 = xc[lane];
            const float x1 = xc[64 + lane];
            const float x2 = xc[128 + lane];
            const float x3 = xc[192 + (lane & 3)];   // only lanes<4 real
            const float* wc = wpb + c * 14;
            #pragma unroll
            for (int i = 0; i < 14; ++i) {
                const float w = wc[i];               // wave-uniform LDS broadcast
                pc0[i] = fmaf(w, x0, pc0[i]);
                pc1[i] = fmaf(w, x1, pc1[i]);
                pc2[i] = fmaf(w, x2, pc2[i]);
                pc3[i] = fmaf(w, x3, pc3[i]);
            }
        }

        // emit: squash + caps matvec into u registers
        #define EMIT(PC, R)                                                     \
        {                                                                       \
            const int hw = (R) * 64 + lane;                                     \
            if (hw < 196) {                                                     \
                const int n = g * 196 + hw;                                     \
                float sq = 0.f;                                                 \
                _Pragma("unroll")                                               \
                for (int i = 0; i < 14; ++i) sq = fmaf(PC[i], PC[i], sq);       \
                const float scale = sqrtf(sq) / (1.0f + sq);                    \
                float uo[NCLS] = {0.f, 0.f, 0.f, 0.f, 0.f};                     \
                const float* cw = capsW + (size_t)n * 70;                       \
                _Pragma("unroll")                                               \
                for (int i = 0; i < 14; ++i) {                                  \
                    const float p = PC[i] * scale;                              \
                    _Pragma("unroll")                                           \
                    for (int o = 0; o < NCLS; ++o)                              \
                        uo[o] = fmaf(p, cw[i * 5 + o], uo[o]);                  \
                }                                                               \
                _Pragma("unroll")                                               \
                for (int o = 0; o < NCLS; ++o) u[gi][R][o] = uo[o];             \
            } else {                                                            \
                _Pragma("unroll")                                               \
                for (int o = 0; o < NCLS; ++o) u[gi][R][o] = 0.f;               \
            }                                                                   \
        }
        EMIT(pc0, 0) EMIT(pc1, 1) EMIT(pc2, 2) EMIT(pc3, 3)
        #undef EMIT
    }
    __syncthreads();

    // ---------------- Phase 3: routing (initial + 3 iters), u in regs ------
    float V[NCLS] = {0.f, 0.f, 0.f, 0.f, 0.f};
    for (int it = 0; it < 4; ++it) {
        float sacc[NCLS] = {0.f, 0.f, 0.f, 0.f, 0.f};
        #pragma unroll
        for (int gi = 0; gi < 2; ++gi) {
            const int g = wv + gi * 16;
            #pragma unroll
            for (int r = 0; r < 4; ++r) {
                const int hw = r * 64 + lane;
                if (hw < 196) {
                    const int n = g * 196 + hw;
                    const float* br = broute + (size_t)n * 5;
                    float l[NCLS];
                    #pragma unroll
                    for (int o = 0; o < NCLS; ++o)
                        l[o] = fmaf(u[gi][r][o], V[o], br[o]);
                    const float m = fmaxf(fmaxf(fmaxf(l[0], l[1]), fmaxf(l[2], l[3])), l[4]);
                    float e[NCLS], es = 0.f;
                    #pragma unroll
                    for (int o = 0; o < NCLS; ++o) { e[o] = __expf(l[o] - m); es += e[o]; }
                    const float inv = 1.0f / es;
                    #pragma unroll
                    for (int o = 0; o < NCLS; ++o)
                        sacc[o] = fmaf(u[gi][r][o], e[o] * inv, sacc[o]);
                }
            }
        }
        // wave reduce then cross-wave via LDS
        #pragma unroll
        for (int off = 32; off > 0; off >>= 1)
            #pragma unroll
            for (int o = 0; o < NCLS; ++o)
                sacc[o] += __shfl_down(sacc[o], off);
        if (lane == 0) {
            #pragma unroll
            for (int o = 0; o < NCLS; ++o) s_red[wv * 5 + o] = sacc[o];
        }
        __syncthreads();
        if (tid < NCLS) {
            float s = 0.f;
            for (int w2 = 0; w2 < NW; ++w2) s += s_red[w2 * 5 + tid];
            s_v[tid] = s * fabsf(s) / (1.0f + s * s);   // squash, OUT_DIM=1
        }
        __syncthreads();
        #pragma unroll
        for (int o = 0; o < NCLS; ++o) V[o] += s_v[o];
    }

    if (tid < NCLS) out[b * NCLS + tid] = fabsf(s_v[tid]);
}

extern "C" void kernel_launch(void* const* d_in, const int* in_sizes, int n_in,
                              void* d_out, int out_size, void* d_ws, size_t ws_size,
                              hipStream_t stream)
{
    const float* inp   = (const float*)d_in[0];
    // d_in[1] = r (python scalar, unused by reference)
    const float* W1    = (const float*)d_in[2];
    const float* b1    = (const float*)d_in[3];
    const float* Wp    = (const float*)d_in[4];
    const float* bp    = (const float*)d_in[5];
    const float* capsW = (const float*)d_in[6];
    const float* brt   = (const float*)d_in[7];
    float* out = (float*)d_out;

    const int B = in_sizes[0] / (59 * 59);   // 1024
    const size_t lds_bytes = (size_t)(3481 + 800 + 32 + 448 + 6272 + 7168 + 80 + 8) * sizeof(float);
    (void)hipFuncSetAttribute((const void*)caps_fused,
                              hipFuncAttributeMaxDynamicSharedMemorySize,
                              (int)lds_bytes);
    caps_fused<<<B, NTH, lds_bytes, stream>>>(inp, W1, b1, Wp, bp, capsW, brt, out);
}